// Round 1
// 561.401 us; speedup vs baseline: 1.1337x; 1.1337x over previous
//
#include <hip/hip_runtime.h>

#define S_   512
#define B_   64
#define H_   1024
#define E_   512
#define V_   32000
#define TWOH 2048
#define KIN  2560           // 2H + E
#define KCAT 3584           // 2H + E + H
#define G4   4096
#define NCH  32             // attention S-chunks (one wave each)
#define SPC  (S_ / NCH)     // 16 s per chunk
#define NSPL 4              // gemm_gates K-splits

// ws byte layout (f32 partials)
#define P_STRIDE 8208                        // m,l fp32 + pad to 16 + 2048 f32
#define A1_OFF   16809984                    // 64*32*8208
#define GP_OFF   17268736                    // A1_OFF + 64*3584*2
#define H1_OFF   21463040                    // GP_OFF + 4*64*4096*4
// total ws use: 21,594,112 bytes (~21.6 MB)

typedef unsigned short u16;
typedef unsigned int   u32;

using f32x4 = __attribute__((ext_vector_type(4))) float;
using s16x8 = __attribute__((ext_vector_type(8))) short;

__device__ __forceinline__ u16 f2bf(float f) {
    union { float f; u32 u; } v; v.f = f;
    u32 r = v.u + 0x7fffu + ((v.u >> 16) & 1u);
    return (u16)(r >> 16);
}
__device__ __forceinline__ s16x8 pack_frag(const float* p) {
    s16x8 r;
#pragma unroll
    for (int j = 0; j < 8; j++) r[j] = (short)f2bf(p[j]);
    return r;
}

// K1: one wave per (b, s-chunk). Online-softmax partial over 16 s values.
// Lane t-element mapping: d = j*256 + lane*4 + c  (8 float4 chunks per 2048 row)
__global__ __launch_bounds__(64)
void attn_partial(const float* __restrict__ enc, const float* __restrict__ h0,
                  const float* __restrict__ Wen, const float* __restrict__ be,
                  char* __restrict__ wsP) {
    const int b = blockIdx.y, ch = blockIdx.x, lane = threadIdx.x;

    // w_e fragment (32 of 2048)
    float we[32];
#pragma unroll
    for (int j = 0; j < 8; j++)
        *(float4*)&we[j * 4] = *(const float4*)(Wen + H_ + j * 256 + lane * 4);

    // hd = h0[b] . w_h + b_energy
    float hd = 0.f;
#pragma unroll
    for (int j = 0; j < 4; j++) {
        const float4 hv = *(const float4*)(h0 + b * H_ + j * 256 + lane * 4);
        const float4 wv = *(const float4*)(Wen + j * 256 + lane * 4);
        hd += hv.x * wv.x + hv.y * wv.y + hv.z * wv.z + hv.w * wv.w;
    }
    for (int off = 32; off > 0; off >>= 1) hd += __shfl_xor(hd, off, 64);
    hd += be[0];

    float m = -1e30f, l = 0.f, ctx[32];
#pragma unroll
    for (int i = 0; i < 32; i++) ctx[i] = 0.f;

    const int s0 = ch * SPC;
    for (int si = 0; si < SPC; si++) {
        const float* eb = enc + ((size_t)(s0 + si) * B_ + b) * TWOH;
        float ev[32];
#pragma unroll
        for (int j = 0; j < 8; j++)
            *(float4*)&ev[j * 4] = *(const float4*)(eb + j * 256 + lane * 4);
        float dot = 0.f;
#pragma unroll
        for (int i = 0; i < 32; i++) dot += ev[i] * we[i];
        for (int off = 32; off > 0; off >>= 1) dot += __shfl_xor(dot, off, 64);
        const float e  = fmaxf(dot + hd, 0.f);
        const float mn = fmaxf(m, e);
        const float al = __expf(m - mn), p = __expf(e - mn);
        l = l * al + p;
#pragma unroll
        for (int i = 0; i < 32; i++) ctx[i] = ctx[i] * al + p * ev[i];
        m = mn;
    }

    char* pb = wsP + (size_t)(b * NCH + ch) * P_STRIDE;
    if (lane == 0) { ((float*)pb)[0] = m; ((float*)pb)[1] = l; }
    float* pc = (float*)(pb + 16);
#pragma unroll
    for (int j = 0; j < 8; j++)
        *(float4*)(pc + j * 256 + lane * 4) = *(const float4*)&ctx[j * 4];
}

// K2: merge 32 partials per b; build A1 = [context | emb[x[b]] | h0] bf16 (64 x 3584)
__global__ __launch_bounds__(256)
void attn_merge(const char* __restrict__ wsP, u16* __restrict__ A1,
                const int* __restrict__ x, const float* __restrict__ emb,
                const float* __restrict__ h0) {
    const int b = blockIdx.x, t = threadIdx.x;
    __shared__ float sm[NCH], sl[NCH];
    if (t < NCH) {
        const float* pf = (const float*)(wsP + (size_t)(b * NCH + t) * P_STRIDE);
        sm[t] = pf[0]; sl[t] = pf[1];
    }
    __syncthreads();
    float M = -1e30f;
    for (int i = 0; i < NCH; i++) M = fmaxf(M, sm[i]);
    float L = 0.f;
    for (int i = 0; i < NCH; i++) L += sl[i] * __expf(sm[i] - M);
    const float inv = 1.f / L;

    float acc[8];
#pragma unroll
    for (int q = 0; q < 8; q++) acc[q] = 0.f;
    const int d = t * 8;
    for (int i = 0; i < NCH; i++) {
        const float w = __expf(sm[i] - M);
        const float* pc = (const float*)(wsP + (size_t)(b * NCH + i) * P_STRIDE + 16);
        const float4 v0 = *(const float4*)(pc + d);
        const float4 v1 = *(const float4*)(pc + d + 4);
        acc[0] += w * v0.x; acc[1] += w * v0.y; acc[2] += w * v0.z; acc[3] += w * v0.w;
        acc[4] += w * v1.x; acc[5] += w * v1.y; acc[6] += w * v1.z; acc[7] += w * v1.w;
    }
#pragma unroll
    for (int q = 0; q < 8; q++) acc[q] *= inv;

    u16* row = A1 + b * KCAT;
    uint4 cw;
    cw.x = (u32)f2bf(acc[0]) | ((u32)f2bf(acc[1]) << 16);
    cw.y = (u32)f2bf(acc[2]) | ((u32)f2bf(acc[3]) << 16);
    cw.z = (u32)f2bf(acc[4]) | ((u32)f2bf(acc[5]) << 16);
    cw.w = (u32)f2bf(acc[6]) | ((u32)f2bf(acc[7]) << 16);
    *(uint4*)(row + d) = cw;
    // emb gather (512 els, 2/thread)
    const int xb = x[b];
    const float2 ev = *(const float2*)(emb + (size_t)xb * E_ + t * 2);
    *(u32*)(row + TWOH + t * 2) = (u32)f2bf(ev.x) | ((u32)f2bf(ev.y) << 16);
    // h0 copy (1024 els, 4/thread)
    const float4 hv = *(const float4*)(h0 + b * H_ + t * 4);
    uint2 hw;
    hw.x = (u32)f2bf(hv.x) | ((u32)f2bf(hv.y) << 16);
    hw.y = (u32)f2bf(hv.z) | ((u32)f2bf(hv.w) << 16);
    *(uint2*)(row + KIN + t * 4) = hw;
}

// K3: gates = A1 @ [W_ih | W_hh]^T, MFMA 16x16x32 bf16, M=64, wave tile 64x16.
// K-split x4 aligned to the Wih|Whh seam (0,896,1792,2560,3584) -> 256 blocks
// (fills all 256 CUs; old 2-split left half the chip idle). 64-k superstep
// issues all 4 W loads + 8 A-frag loads before the dependent pack->MFMA chain.
__global__ __launch_bounds__(256)
void gemm_gates(const u16* __restrict__ A1, const float* __restrict__ Wih,
                const float* __restrict__ Whh, float* __restrict__ gp) {
    const int wave = threadIdx.x >> 6, lane = threadIdx.x & 63;
    const int quad = lane >> 4, l16 = lane & 15;
    const int n0 = blockIdx.x * 64 + wave * 16;
    const int split = blockIdx.y;
    const int kbeg = (split == 0) ? 0   : (split == 1) ? 896  : (split == 2) ? 1792 : 2560;
    const int kend = (split == 0) ? 896 : (split == 1) ? 1792 : (split == 2) ? 2560 : 3584;
    const int r = n0 + l16;
    // branch-free weight base for this split (splits 0-2: Wih, split 3: Whh)
    const float* __restrict__ Wr = (split < 3) ? (Wih + (size_t)r * KIN)
                                               : (Whh + (size_t)r * H_);
    const int koff = (split < 3) ? 0 : KIN;

    f32x4 acc[4];
#pragma unroll
    for (int mi = 0; mi < 4; mi++) acc[mi] = (f32x4){0.f, 0.f, 0.f, 0.f};

    for (int k = kbeg; k < kend; k += 64) {
        const int kq0 = k + quad * 8, kq1 = kq0 + 32;
        // issue all global loads for the 64-k superstep up front
        float wv0[8], wv1[8];
        *(float4*)&wv0[0] = *(const float4*)(Wr + (kq0 - koff));
        *(float4*)&wv0[4] = *(const float4*)(Wr + (kq0 - koff) + 4);
        *(float4*)&wv1[0] = *(const float4*)(Wr + (kq1 - koff));
        *(float4*)&wv1[4] = *(const float4*)(Wr + (kq1 - koff) + 4);
        s16x8 a0[4], a1[4];
#pragma unroll
        for (int mi = 0; mi < 4; mi++) {
            a0[mi] = *(const s16x8*)(A1 + (size_t)(mi * 16 + l16) * KCAT + kq0);
            a1[mi] = *(const s16x8*)(A1 + (size_t)(mi * 16 + l16) * KCAT + kq1);
        }
        const s16x8 b0 = pack_frag(wv0);
#pragma unroll
        for (int mi = 0; mi < 4; mi++)
            acc[mi] = __builtin_amdgcn_mfma_f32_16x16x32_bf16(a0[mi], b0, acc[mi], 0, 0, 0);
        const s16x8 b1 = pack_frag(wv1);
#pragma unroll
        for (int mi = 0; mi < 4; mi++)
            acc[mi] = __builtin_amdgcn_mfma_f32_16x16x32_bf16(a1[mi], b1, acc[mi], 0, 0, 0);
    }
    float* out = gp + (size_t)split * B_ * G4;
#pragma unroll
    for (int mi = 0; mi < 4; mi++)
#pragma unroll
        for (int reg = 0; reg < 4; reg++)
            out[(size_t)(mi * 16 + quad * 4 + reg) * G4 + n0 + l16] = acc[mi][reg];
}

// K4: LSTM elementwise epilogue (f32 out), sums 4 K-split partials
__global__ __launch_bounds__(256)
void lstm_ep(const float* __restrict__ gp, const float* __restrict__ bih,
             const float* __restrict__ bhh, const float* __restrict__ c0,
             float* __restrict__ out, u16* __restrict__ h1b) {
    const int idx = blockIdx.x * 256 + threadIdx.x;
    const int b = idx >> 10, u = idx & 1023;
    const size_t sb = (size_t)B_ * G4;
    const float* g0 = gp + (size_t)b * G4;
    float gi = bih[u]        + bhh[u];
    float gf = bih[u + 1024] + bhh[u + 1024];
    float gg = bih[u + 2048] + bhh[u + 2048];
    float go = bih[u + 3072] + bhh[u + 3072];
#pragma unroll
    for (int s = 0; s < NSPL; s++) {
        const float* g = g0 + s * sb;
        gi += g[u];
        gf += g[u + 1024];
        gg += g[u + 2048];
        go += g[u + 3072];
    }
    const float c0v = c0[idx];
    const float si = 1.f / (1.f + __expf(-gi));
    const float sf = 1.f / (1.f + __expf(-gf));
    const float so = 1.f / (1.f + __expf(-go));
    const float c1 = sf * c0v + si * tanhf(gg);
    const float h1 = so * tanhf(c1);
    out[2048000 + idx] = h1;
    out[2113536 + idx] = c1;
    h1b[idx] = f2bf(h1);
}

// K5: pred = h1 @ W_fc^T + b_fc, MFMA, M=64, wave tile 64x16, 500 blocks.
// 64-k superstep: all 4 Wfc loads + 8 A-frag loads in flight before pack->MFMA.
__global__ __launch_bounds__(256)
void gemm_fc(const u16* __restrict__ h1b, const float* __restrict__ Wfc,
             const float* __restrict__ bfc, float* __restrict__ pred) {
    const int wave = threadIdx.x >> 6, lane = threadIdx.x & 63;
    const int quad = lane >> 4, l16 = lane & 15;
    const int n0 = blockIdx.x * 64 + wave * 16;
    const int r = n0 + l16;
    const float* __restrict__ Wr = Wfc + (size_t)r * H_;

    f32x4 acc[4];
#pragma unroll
    for (int mi = 0; mi < 4; mi++) acc[mi] = (f32x4){0.f, 0.f, 0.f, 0.f};

    for (int k = 0; k < H_; k += 64) {
        const int kq0 = k + quad * 8, kq1 = kq0 + 32;
        float wv0[8], wv1[8];
        *(float4*)&wv0[0] = *(const float4*)(Wr + kq0);
        *(float4*)&wv0[4] = *(const float4*)(Wr + kq0 + 4);
        *(float4*)&wv1[0] = *(const float4*)(Wr + kq1);
        *(float4*)&wv1[4] = *(const float4*)(Wr + kq1 + 4);
        s16x8 a0[4], a1[4];
#pragma unroll
        for (int mi = 0; mi < 4; mi++) {
            a0[mi] = *(const s16x8*)(h1b + (size_t)(mi * 16 + l16) * H_ + kq0);
            a1[mi] = *(const s16x8*)(h1b + (size_t)(mi * 16 + l16) * H_ + kq1);
        }
        const s16x8 b0 = pack_frag(wv0);
#pragma unroll
        for (int mi = 0; mi < 4; mi++)
            acc[mi] = __builtin_amdgcn_mfma_f32_16x16x32_bf16(a0[mi], b0, acc[mi], 0, 0, 0);
        const s16x8 b1 = pack_frag(wv1);
#pragma unroll
        for (int mi = 0; mi < 4; mi++)
            acc[mi] = __builtin_amdgcn_mfma_f32_16x16x32_bf16(a1[mi], b1, acc[mi], 0, 0, 0);
    }
    const float bv = bfc[r];
#pragma unroll
    for (int mi = 0; mi < 4; mi++)
#pragma unroll
        for (int reg = 0; reg < 4; reg++)
            pred[(size_t)(mi * 16 + quad * 4 + reg) * V_ + n0 + l16] = acc[mi][reg] + bv;
}

extern "C" void kernel_launch(void* const* d_in, const int* in_sizes, int n_in,
                              void* d_out, int out_size, void* d_ws, size_t ws_size,
                              hipStream_t stream) {
    const int*   x   = (const int*)d_in[0];
    const float* enc = (const float*)d_in[1];
    const float* hid = (const float*)d_in[2];
    const float* cel = (const float*)d_in[3];
    const float* emb = (const float*)d_in[4];
    const float* Wen = (const float*)d_in[5];
    const float* be  = (const float*)d_in[6];
    const float* Wih = (const float*)d_in[7];
    const float* Whh = (const float*)d_in[8];
    const float* bih = (const float*)d_in[9];
    const float* bhh = (const float*)d_in[10];
    const float* Wfc = (const float*)d_in[11];
    const float* bfc = (const float*)d_in[12];
    float* out = (float*)d_out;
    char*  ws  = (char*)d_ws;

    char*  wsP = ws;
    u16*   A1  = (u16*)(ws + A1_OFF);
    float* gp  = (float*)(ws + GP_OFF);
    u16*   h1b = (u16*)(ws + H1_OFF);

    attn_partial<<<dim3(NCH, B_), dim3(64), 0, stream>>>(enc, hid, Wen, be, wsP);
    attn_merge  <<<dim3(B_),      dim3(256), 0, stream>>>(wsP, A1, x, emb, hid);
    gemm_gates  <<<dim3(G4 / 64, NSPL), dim3(256), 0, stream>>>(A1, Wih, Whh, gp);
    lstm_ep     <<<dim3((B_ * H_) / 256), dim3(256), 0, stream>>>(gp, bih, bhh, cel, out, h1b);
    gemm_fc     <<<dim3(V_ / 64), dim3(256), 0, stream>>>(h1b, Wfc, bfc, out);
}

// Round 3
// 550.851 us; speedup vs baseline: 1.1554x; 1.0192x over previous
//
#include <hip/hip_runtime.h>

#define S_   512
#define B_   64
#define H_   1024
#define E_   512
#define V_   32000
#define TWOH 2048
#define KIN  2560           // 2H + E
#define KCAT 3584           // 2H + E + H
#define G4   4096
#define NCH  32             // attention S-chunks (one wave each)
#define SPC  (S_ / NCH)     // 16 s per chunk
#define NSPL 4              // gemm_gates K-splits

// ws byte layout (f32 partials)
#define P_STRIDE 8208                        // m,l fp32 + pad to 16 + 2048 f32
#define A1_OFF   16809984                    // 64*32*8208
#define GP_OFF   17268736                    // A1_OFF + 64*3584*2
#define H1_OFF   21463040                    // GP_OFF + 4*64*4096*4
// total ws use: 21,594,112 bytes (~21.6 MB)

typedef unsigned short u16;
typedef unsigned int   u32;

using f32x4 = __attribute__((ext_vector_type(4))) float;   // native vector: ok for nontemporal builtins
using s16x8 = __attribute__((ext_vector_type(8))) short;

__device__ __forceinline__ u16 f2bf(float f) {
    union { float f; u32 u; } v; v.f = f;
    u32 r = v.u + 0x7fffu + ((v.u >> 16) & 1u);
    return (u16)(r >> 16);
}
__device__ __forceinline__ s16x8 pack2(f32x4 a, f32x4 b) {
    s16x8 r;
    r[0] = (short)f2bf(a[0]); r[1] = (short)f2bf(a[1]);
    r[2] = (short)f2bf(a[2]); r[3] = (short)f2bf(a[3]);
    r[4] = (short)f2bf(b[0]); r[5] = (short)f2bf(b[1]);
    r[6] = (short)f2bf(b[2]); r[7] = (short)f2bf(b[3]);
    return r;
}

// K1: one wave per (b, s-chunk). Online-softmax partial over 16 s values.
// Grid is (b, ch) so consecutive blocks share an s-window: the 64 blocks of one
// ch read a contiguous 8 MB enc region (DRAM locality), and the XCD round-robin
// hands each XCD disjoint b-rows. enc is single-pass -> nontemporal loads.
__global__ __launch_bounds__(64)
void attn_partial(const float* __restrict__ enc, const float* __restrict__ h0,
                  const float* __restrict__ Wen, const float* __restrict__ be,
                  char* __restrict__ wsP) {
    const int b = blockIdx.x, ch = blockIdx.y, lane = threadIdx.x;

    // w_e fragment (32 of 2048)
    float we[32];
#pragma unroll
    for (int j = 0; j < 8; j++)
        *(f32x4*)&we[j * 4] = *(const f32x4*)(Wen + H_ + j * 256 + lane * 4);

    // hd = h0[b] . w_h + b_energy
    float hd = 0.f;
#pragma unroll
    for (int j = 0; j < 4; j++) {
        const f32x4 hv = *(const f32x4*)(h0 + b * H_ + j * 256 + lane * 4);
        const f32x4 wv = *(const f32x4*)(Wen + j * 256 + lane * 4);
        hd += hv[0] * wv[0] + hv[1] * wv[1] + hv[2] * wv[2] + hv[3] * wv[3];
    }
    for (int off = 32; off > 0; off >>= 1) hd += __shfl_xor(hd, off, 64);
    hd += be[0];

    float m = -1e30f, l = 0.f, ctx[32];
#pragma unroll
    for (int i = 0; i < 32; i++) ctx[i] = 0.f;

    const int s0 = ch * SPC;
    for (int si = 0; si < SPC; si++) {
        const float* eb = enc + ((size_t)(s0 + si) * B_ + b) * TWOH;
        float ev[32];
#pragma unroll
        for (int j = 0; j < 8; j++) {
            const f32x4 t = __builtin_nontemporal_load((const f32x4*)(eb + j * 256 + lane * 4));
            *(f32x4*)&ev[j * 4] = t;
        }
        float dot = 0.f;
#pragma unroll
        for (int i = 0; i < 32; i++) dot += ev[i] * we[i];
        for (int off = 32; off > 0; off >>= 1) dot += __shfl_xor(dot, off, 64);
        const float e  = fmaxf(dot + hd, 0.f);
        const float mn = fmaxf(m, e);
        const float al = __expf(m - mn), p = __expf(e - mn);
        l = l * al + p;
#pragma unroll
        for (int i = 0; i < 32; i++) ctx[i] = ctx[i] * al + p * ev[i];
        m = mn;
    }

    char* pb = wsP + (size_t)(b * NCH + ch) * P_STRIDE;
    if (lane == 0) { ((float*)pb)[0] = m; ((float*)pb)[1] = l; }
    float* pc = (float*)(pb + 16);
#pragma unroll
    for (int j = 0; j < 8; j++)
        *(f32x4*)(pc + j * 256 + lane * 4) = *(const f32x4*)&ctx[j * 4];
}

// K2: merge 32 partials per b; build A1 = [context | emb[x[b]] | h0] bf16 (64 x 3584)
__global__ __launch_bounds__(256)
void attn_merge(const char* __restrict__ wsP, u16* __restrict__ A1,
                const int* __restrict__ x, const float* __restrict__ emb,
                const float* __restrict__ h0) {
    const int b = blockIdx.x, t = threadIdx.x;
    __shared__ float sm[NCH], sl[NCH];
    if (t < NCH) {
        const float* pf = (const float*)(wsP + (size_t)(b * NCH + t) * P_STRIDE);
        sm[t] = pf[0]; sl[t] = pf[1];
    }
    __syncthreads();
    float M = -1e30f;
    for (int i = 0; i < NCH; i++) M = fmaxf(M, sm[i]);
    float L = 0.f;
    for (int i = 0; i < NCH; i++) L += sl[i] * __expf(sm[i] - M);
    const float inv = 1.f / L;

    float acc[8];
#pragma unroll
    for (int q = 0; q < 8; q++) acc[q] = 0.f;
    const int d = t * 8;
    for (int i = 0; i < NCH; i++) {
        const float w = __expf(sm[i] - M);
        const float* pc = (const float*)(wsP + (size_t)(b * NCH + i) * P_STRIDE + 16);
        const f32x4 v0 = *(const f32x4*)(pc + d);
        const f32x4 v1 = *(const f32x4*)(pc + d + 4);
        acc[0] += w * v0[0]; acc[1] += w * v0[1]; acc[2] += w * v0[2]; acc[3] += w * v0[3];
        acc[4] += w * v1[0]; acc[5] += w * v1[1]; acc[6] += w * v1[2]; acc[7] += w * v1[3];
    }
#pragma unroll
    for (int q = 0; q < 8; q++) acc[q] *= inv;

    u16* row = A1 + b * KCAT;
    uint4 cw;
    cw.x = (u32)f2bf(acc[0]) | ((u32)f2bf(acc[1]) << 16);
    cw.y = (u32)f2bf(acc[2]) | ((u32)f2bf(acc[3]) << 16);
    cw.z = (u32)f2bf(acc[4]) | ((u32)f2bf(acc[5]) << 16);
    cw.w = (u32)f2bf(acc[6]) | ((u32)f2bf(acc[7]) << 16);
    *(uint4*)(row + d) = cw;
    // emb gather (512 els, 2/thread)
    const int xb = x[b];
    const float2 ev = *(const float2*)(emb + (size_t)xb * E_ + t * 2);
    *(u32*)(row + TWOH + t * 2) = (u32)f2bf(ev.x) | ((u32)f2bf(ev.y) << 16);
    // h0 copy (1024 els, 4/thread)
    const f32x4 hv = *(const f32x4*)(h0 + b * H_ + t * 4);
    uint2 hw;
    hw.x = (u32)f2bf(hv[0]) | ((u32)f2bf(hv[1]) << 16);
    hw.y = (u32)f2bf(hv[2]) | ((u32)f2bf(hv[3]) << 16);
    *(uint2*)(row + KIN + t * 4) = hw;
}

// K3: gates = A1 @ [W_ih | W_hh]^T, MFMA 16x16x32 bf16, M=64, wave tile 64x16.
// K-split x4 aligned to the Wih|Whh seam (0,896,1792,2560,3584) -> 256 blocks.
// 64-k superstep issues all 4 W loads + 8 A-frag loads before pack->MFMA.
// W is single-pass -> nontemporal (keeps A1 hot in L2).
__global__ __launch_bounds__(256)
void gemm_gates(const u16* __restrict__ A1, const float* __restrict__ Wih,
                const float* __restrict__ Whh, float* __restrict__ gp) {
    const int wave = threadIdx.x >> 6, lane = threadIdx.x & 63;
    const int quad = lane >> 4, l16 = lane & 15;
    const int n0 = blockIdx.x * 64 + wave * 16;
    const int split = blockIdx.y;
    const int kbeg = (split == 0) ? 0   : (split == 1) ? 896  : (split == 2) ? 1792 : 2560;
    const int kend = (split == 0) ? 896 : (split == 1) ? 1792 : (split == 2) ? 2560 : 3584;
    const int r = n0 + l16;
    // branch-free weight base for this split (splits 0-2: Wih, split 3: Whh)
    const float* __restrict__ Wr = (split < 3) ? (Wih + (size_t)r * KIN)
                                               : (Whh + (size_t)r * H_);
    const int koff = (split < 3) ? 0 : KIN;

    f32x4 acc[4];
#pragma unroll
    for (int mi = 0; mi < 4; mi++) acc[mi] = (f32x4){0.f, 0.f, 0.f, 0.f};

    for (int k = kbeg; k < kend; k += 64) {
        const int kq0 = k + quad * 8, kq1 = kq0 + 32;
        // issue all global loads for the 64-k superstep up front
        const f32x4 w00 = __builtin_nontemporal_load((const f32x4*)(Wr + (kq0 - koff)));
        const f32x4 w01 = __builtin_nontemporal_load((const f32x4*)(Wr + (kq0 - koff) + 4));
        const f32x4 w10 = __builtin_nontemporal_load((const f32x4*)(Wr + (kq1 - koff)));
        const f32x4 w11 = __builtin_nontemporal_load((const f32x4*)(Wr + (kq1 - koff) + 4));
        s16x8 a0[4], a1[4];
#pragma unroll
        for (int mi = 0; mi < 4; mi++) {
            a0[mi] = *(const s16x8*)(A1 + (size_t)(mi * 16 + l16) * KCAT + kq0);
            a1[mi] = *(const s16x8*)(A1 + (size_t)(mi * 16 + l16) * KCAT + kq1);
        }
        const s16x8 b0 = pack2(w00, w01);
#pragma unroll
        for (int mi = 0; mi < 4; mi++)
            acc[mi] = __builtin_amdgcn_mfma_f32_16x16x32_bf16(a0[mi], b0, acc[mi], 0, 0, 0);
        const s16x8 b1 = pack2(w10, w11);
#pragma unroll
        for (int mi = 0; mi < 4; mi++)
            acc[mi] = __builtin_amdgcn_mfma_f32_16x16x32_bf16(a1[mi], b1, acc[mi], 0, 0, 0);
    }
    float* out = gp + (size_t)split * B_ * G4;
#pragma unroll
    for (int mi = 0; mi < 4; mi++)
#pragma unroll
        for (int reg = 0; reg < 4; reg++)
            out[(size_t)(mi * 16 + quad * 4 + reg) * G4 + n0 + l16] = acc[mi][reg];
}

// K4: LSTM elementwise epilogue (f32 out), sums 4 K-split partials.
// h1/c1 outputs are never re-read on-device -> nontemporal stores.
__global__ __launch_bounds__(256)
void lstm_ep(const float* __restrict__ gp, const float* __restrict__ bih,
             const float* __restrict__ bhh, const float* __restrict__ c0,
             float* __restrict__ out, u16* __restrict__ h1b) {
    const int idx = blockIdx.x * 256 + threadIdx.x;
    const int b = idx >> 10, u = idx & 1023;
    const size_t sb = (size_t)B_ * G4;
    const float* g0 = gp + (size_t)b * G4;
    float gi = bih[u]        + bhh[u];
    float gf = bih[u + 1024] + bhh[u + 1024];
    float gg = bih[u + 2048] + bhh[u + 2048];
    float go = bih[u + 3072] + bhh[u + 3072];
#pragma unroll
    for (int s = 0; s < NSPL; s++) {
        const float* g = g0 + s * sb;
        gi += g[u];
        gf += g[u + 1024];
        gg += g[u + 2048];
        go += g[u + 3072];
    }
    const float c0v = c0[idx];
    const float si = 1.f / (1.f + __expf(-gi));
    const float sf = 1.f / (1.f + __expf(-gf));
    const float so = 1.f / (1.f + __expf(-go));
    const float c1 = sf * c0v + si * tanhf(gg);
    const float h1 = so * tanhf(c1);
    __builtin_nontemporal_store(h1, out + 2048000 + idx);
    __builtin_nontemporal_store(c1, out + 2113536 + idx);
    h1b[idx] = f2bf(h1);
}

// K5: pred = h1 @ W_fc^T + b_fc, MFMA, M=64, wave tile 64x16, 500 blocks.
// 64-k superstep; Wfc single-pass -> nontemporal loads (keeps h1b hot);
// pred never re-read -> nontemporal stores.
__global__ __launch_bounds__(256)
void gemm_fc(const u16* __restrict__ h1b, const float* __restrict__ Wfc,
             const float* __restrict__ bfc, float* __restrict__ pred) {
    const int wave = threadIdx.x >> 6, lane = threadIdx.x & 63;
    const int quad = lane >> 4, l16 = lane & 15;
    const int n0 = blockIdx.x * 64 + wave * 16;
    const int r = n0 + l16;
    const float* __restrict__ Wr = Wfc + (size_t)r * H_;

    f32x4 acc[4];
#pragma unroll
    for (int mi = 0; mi < 4; mi++) acc[mi] = (f32x4){0.f, 0.f, 0.f, 0.f};

    for (int k = 0; k < H_; k += 64) {
        const int kq0 = k + quad * 8, kq1 = kq0 + 32;
        const f32x4 w00 = __builtin_nontemporal_load((const f32x4*)(Wr + kq0));
        const f32x4 w01 = __builtin_nontemporal_load((const f32x4*)(Wr + kq0 + 4));
        const f32x4 w10 = __builtin_nontemporal_load((const f32x4*)(Wr + kq1));
        const f32x4 w11 = __builtin_nontemporal_load((const f32x4*)(Wr + kq1 + 4));
        s16x8 a0[4], a1[4];
#pragma unroll
        for (int mi = 0; mi < 4; mi++) {
            a0[mi] = *(const s16x8*)(h1b + (size_t)(mi * 16 + l16) * H_ + kq0);
            a1[mi] = *(const s16x8*)(h1b + (size_t)(mi * 16 + l16) * H_ + kq1);
        }
        const s16x8 b0 = pack2(w00, w01);
#pragma unroll
        for (int mi = 0; mi < 4; mi++)
            acc[mi] = __builtin_amdgcn_mfma_f32_16x16x32_bf16(a0[mi], b0, acc[mi], 0, 0, 0);
        const s16x8 b1 = pack2(w10, w11);
#pragma unroll
        for (int mi = 0; mi < 4; mi++)
            acc[mi] = __builtin_amdgcn_mfma_f32_16x16x32_bf16(a1[mi], b1, acc[mi], 0, 0, 0);
    }
    const float bv = bfc[r];
#pragma unroll
    for (int mi = 0; mi < 4; mi++)
#pragma unroll
        for (int reg = 0; reg < 4; reg++)
            __builtin_nontemporal_store(acc[mi][reg] + bv,
                pred + (size_t)(mi * 16 + quad * 4 + reg) * V_ + n0 + l16);
}

extern "C" void kernel_launch(void* const* d_in, const int* in_sizes, int n_in,
                              void* d_out, int out_size, void* d_ws, size_t ws_size,
                              hipStream_t stream) {
    const int*   x   = (const int*)d_in[0];
    const float* enc = (const float*)d_in[1];
    const float* hid = (const float*)d_in[2];
    const float* cel = (const float*)d_in[3];
    const float* emb = (const float*)d_in[4];
    const float* Wen = (const float*)d_in[5];
    const float* be  = (const float*)d_in[6];
    const float* Wih = (const float*)d_in[7];
    const float* Whh = (const float*)d_in[8];
    const float* bih = (const float*)d_in[9];
    const float* bhh = (const float*)d_in[10];
    const float* Wfc = (const float*)d_in[11];
    const float* bfc = (const float*)d_in[12];
    float* out = (float*)d_out;
    char*  ws  = (char*)d_ws;

    char*  wsP = ws;
    u16*   A1  = (u16*)(ws + A1_OFF);
    float* gp  = (float*)(ws + GP_OFF);
    u16*   h1b = (u16*)(ws + H1_OFF);

    attn_partial<<<dim3(B_, NCH), dim3(64), 0, stream>>>(enc, hid, Wen, be, wsP);
    attn_merge  <<<dim3(B_),      dim3(256), 0, stream>>>(wsP, A1, x, emb, hid);
    gemm_gates  <<<dim3(G4 / 64, NSPL), dim3(256), 0, stream>>>(A1, Wih, Whh, gp);
    lstm_ep     <<<dim3((B_ * H_) / 256), dim3(256), 0, stream>>>(gp, bih, bhh, cel, out, h1b);
    gemm_fc     <<<dim3(V_ / 64), dim3(256), 0, stream>>>(h1b, Wfc, bfc, out);
}